// Round 3
// baseline (668.549 us; speedup 1.0000x reference)
//
#include <hip/hip_runtime.h>
#include <hip/hip_bf16.h>

#define EPSV 1e-5f

typedef __attribute__((ext_vector_type(8))) short bf16x8;
typedef __attribute__((ext_vector_type(16))) float f32x16;

static __device__ __forceinline__ short f2bf(float f) {
    __hip_bfloat16 b = __float2bfloat16(f);
    return __builtin_bit_cast(short, b);
}
static __device__ __forceinline__ float bf2f(short s) {
    unsigned u = ((unsigned)(unsigned short)s) << 16;
    return __builtin_bit_cast(float, u);
}

// f32 -> bf16 bulk convert
__global__ void k_cvt(const float* __restrict__ x, short* __restrict__ xb, int n) {
    int i = blockIdx.x * blockDim.x + threadIdx.x;
    if (i < n) xb[i] = f2bf(x[i]);
}

// w2t[h][o][i] = bf16(w2[h][i*64+o]) for h<64 ; b2[i*64+o] for h==64
template <int CIN>
__global__ void k_prep_w2(const float* __restrict__ w2, const float* __restrict__ b2,
                          short* __restrict__ w2t) {
    int idx = blockIdx.x * blockDim.x + threadIdx.x;
    int total = 65 * 64 * CIN;
    if (idx >= total) return;
    int i = idx % CIN;
    int rest = idx / CIN;
    int o = rest & 63;
    int h = rest >> 6;
    float v = (h < 64) ? w2[(size_t)h * (CIN * 64) + i * 64 + o] : b2[i * 64 + o];
    w2t[idx] = f2bf(v);
}

// zgb[h*E + e] = bf16(relu(b1[h] + sum_i ea[e*16+i] * w1[i*64+h]))
__global__ void k_edge_mlp(const float* __restrict__ ea, const float* __restrict__ w1,
                           const float* __restrict__ b1, short* __restrict__ zgb, int E) {
    __shared__ float sEA[64][17];
    int t = threadIdx.x;
    int e0 = blockIdx.x * 64;
    for (int f = t; f < 64 * 16; f += 256) {
        int e = f >> 4, i = f & 15;
        int ge = e0 + e;
        sEA[e][i] = (ge < E) ? ea[(size_t)ge * 16 + i] : 0.f;
    }
    __syncthreads();
    int lane = t & 63, w = t >> 6;
    int ge = e0 + lane;
    #pragma unroll
    for (int hh = 0; hh < 16; ++hh) {
        int h = w * 16 + hh;
        float acc = b1[h];
        #pragma unroll
        for (int i = 0; i < 16; ++i) acc += sEA[lane][i] * w1[i * 64 + h];
        if (ge < E) zgb[(size_t)h * E + ge] = f2bf(fmaxf(acc, 0.f));
    }
}

// out[n*64+o] = bias[o] + sum_i hin[n*CIN+i] * root[i*64+o]   (inits agg)
template <int CIN>
__global__ void k_root(const float* __restrict__ hin, const float* __restrict__ root,
                       const float* __restrict__ bias, float* __restrict__ out, int N) {
    int idx = blockIdx.x * blockDim.x + threadIdx.x;
    int n = idx >> 6, o = idx & 63;
    if (n >= N) return;
    float acc = bias[o];
    #pragma unroll
    for (int i = 0; i < CIN; ++i) acc += hin[(size_t)n * CIN + i] * root[i * 64 + o];
    out[(size_t)n * 64 + o] = acc;
}

// MFMA message kernel v2: A = W2_h^T (o x i) from L2, B = x^T (i x e) fixed in regs.
// Per h: T = A_h * B (pure MFMA chain), acc[r] += z[e,h] * T[r] (one scalar/lane).
// Output D[row=o][col=e]; atomic scatter by dst(e).
template <int CIN>
__global__ __launch_bounds__(512, 4) void k_msg(const short* __restrict__ zgb,
                                                const short* __restrict__ xb,
                                                const int* __restrict__ src,
                                                const int* __restrict__ dstv,
                                                const short* __restrict__ w2t,
                                                float* __restrict__ agg, int E) {
    constexpr int CH = CIN / 16;
    __shared__ float sZ[128][66];   // [edge][h], 65 used; 66 keeps float2 aligned, 2-way banks (free)
    int t = threadIdx.x;
    int e0 = blockIdx.x * 128;

    // stage z tile as f32; h==64 row is the b2 term (z=1); invalid edges -> 0
    for (int f = t; f < 65 * 128; f += 512) {
        int h = f >> 7, e = f & 127;
        int ge = e0 + e;
        float v = 0.f;
        if (ge < E) v = (h < 64) ? bf2f(zgb[(size_t)h * E + ge]) : 1.f;
        sZ[e][h] = v;
    }

    int lane = t & 63, w = t >> 6;
    int rowg = w >> 2;            // o half: 0/1
    int colg = w & 3;             // e quarter: 0..3
    int kg = lane >> 5, l31 = lane & 31;
    int orow = rowg * 32 + l31;
    int ecol = colg * 32 + l31;
    int ge = e0 + ecol;

    // B operand: x[src(ecol)][i], fixed across all h
    int srow = src[min(ge, E - 1)];
    bf16x8 xB[CH];
    #pragma unroll
    for (int c = 0; c < CH; ++c)
        xB[c] = *reinterpret_cast<const bf16x8*>(xb + (size_t)srow * CIN + c * 16 + kg * 8);

    __syncthreads();

    const short* ap = w2t + (size_t)orow * CIN + kg * 8;

    f32x16 acc;
    #pragma unroll
    for (int r = 0; r < 16; ++r) acc[r] = 0.f;

    #pragma unroll 1
    for (int h = 0; h < 64; h += 2) {
        bf16x8 a0[CH], a1[CH];
        #pragma unroll
        for (int c = 0; c < CH; ++c) {
            a0[c] = *reinterpret_cast<const bf16x8*>(ap + (size_t)h * (64 * CIN) + c * 16);
            a1[c] = *reinterpret_cast<const bf16x8*>(ap + (size_t)(h + 1) * (64 * CIN) + c * 16);
        }
        float2 zz = *reinterpret_cast<const float2*>(&sZ[ecol][h]);
        f32x16 t0, t1;
        #pragma unroll
        for (int r = 0; r < 16; ++r) { t0[r] = 0.f; t1[r] = 0.f; }
        #pragma unroll
        for (int c = 0; c < CH; ++c) {
            t0 = __builtin_amdgcn_mfma_f32_32x32x16_bf16(a0[c], xB[c], t0, 0, 0, 0);
            t1 = __builtin_amdgcn_mfma_f32_32x32x16_bf16(a1[c], xB[c], t1, 0, 0, 0);
        }
        #pragma unroll
        for (int r = 0; r < 16; ++r) acc[r] += zz.x * t0[r] + zz.y * t1[r];
    }
    {   // h == 64: b2 (z staged as 1.0, or 0 for invalid edges)
        bf16x8 a0[CH];
        #pragma unroll
        for (int c = 0; c < CH; ++c)
            a0[c] = *reinterpret_cast<const bf16x8*>(ap + (size_t)64 * (64 * CIN) + c * 16);
        float zf = sZ[ecol][64];
        f32x16 t0;
        #pragma unroll
        for (int r = 0; r < 16; ++r) t0[r] = 0.f;
        #pragma unroll
        for (int c = 0; c < CH; ++c)
            t0 = __builtin_amdgcn_mfma_f32_32x32x16_bf16(a0[c], xB[c], t0, 0, 0, 0);
        #pragma unroll
        for (int r = 0; r < 16; ++r) acc[r] += zf * t0[r];
    }

    if (ge < E) {
        int d = dstv[ge];
        float* base = agg + (size_t)d * 64;
        #pragma unroll
        for (int r = 0; r < 16; ++r) {
            int o = (r & 3) + 8 * (r >> 2) + 4 * kg + rowg * 32;
            atomicAdd(base + o, acc[r]);
        }
    }
}

// in-place LayerNorm + ReLU; also emits bf16 copy for next layer's MFMA input
__global__ void k_ln(float* __restrict__ h, const float* __restrict__ g, const float* __restrict__ b,
                     short* __restrict__ hb, int N) {
    int n = blockIdx.x * 4 + (threadIdx.x >> 6);
    int lane = threadIdx.x & 63;
    if (n >= N) return;
    float v = h[(size_t)n * 64 + lane];
    float s = v;
    #pragma unroll
    for (int d = 32; d > 0; d >>= 1) s += __shfl_xor(s, d, 64);
    float mean = s * (1.f / 64.f);
    float dv = v - mean;
    float s2 = dv * dv;
    #pragma unroll
    for (int d = 32; d > 0; d >>= 1) s2 += __shfl_xor(s2, d, 64);
    float var = s2 * (1.f / 64.f);
    float o = fmaxf(dv * rsqrtf(var + EPSV) * g[lane] + b[lane], 0.f);
    h[(size_t)n * 64 + lane] = o;
    hb[(size_t)n * 64 + lane] = f2bf(o);
}

// fused mean-pool (binary search on sorted batch) + MLP head; 4 waves/graph
__global__ void k_pool_head(const float* __restrict__ h, const int* __restrict__ batch,
                            const float* __restrict__ fc1w, const float* __restrict__ fc1b,
                            const float* __restrict__ fc2w, const float* __restrict__ fc2b,
                            float* __restrict__ out, int N) {
    __shared__ float part[4][64];
    __shared__ float sh[64];
    __shared__ float sh2[32];
    int g = blockIdx.x;
    int t = threadIdx.x, lane = t & 63, w = t >> 6;
    int lo = 0, hi = N;
    while (lo < hi) { int m = (lo + hi) >> 1; if (batch[m] < g) lo = m + 1; else hi = m; }
    int s0 = lo;
    hi = N;
    while (lo < hi) { int m = (lo + hi) >> 1; if (batch[m] < g + 1) lo = m + 1; else hi = m; }
    int s1 = lo;
    float s = 0.f;
    for (int n = s0 + w; n < s1; n += 4) s += h[(size_t)n * 64 + lane];
    part[w][lane] = s;
    __syncthreads();
    if (t < 64) {
        float c = fmaxf((float)(s1 - s0), 1.f);
        sh[t] = (part[0][t] + part[1][t] + part[2][t] + part[3][t]) / c;
    }
    __syncthreads();
    if (t < 32) {
        float a = fc1b[t];
        #pragma unroll
        for (int o = 0; o < 64; ++o) a += sh[o] * fc1w[o * 32 + t];
        sh2[t] = fmaxf(a, 0.f);
    }
    __syncthreads();
    if (t == 0) {
        float a = fc2b[0];
        #pragma unroll
        for (int j = 0; j < 32; ++j) a += sh2[j] * fc2w[j];
        out[g] = a;
    }
}

extern "C" void kernel_launch(void* const* d_in, const int* in_sizes, int n_in,
                              void* d_out, int out_size, void* d_ws, size_t ws_size,
                              hipStream_t stream) {
    const float* x     = (const float*)d_in[0];
    const int*   ei    = (const int*)d_in[1];
    const float* ea    = (const float*)d_in[2];
    const int*   batch = (const int*)d_in[3];
    int E = in_sizes[1] / 2;
    int N = in_sizes[3];
    int G = out_size;  // DOUT = 1
    const int* src  = ei;
    const int* dstv = ei + E;

    const float* P[24];
    for (int i = 0; i < 24; ++i) P[i] = (const float*)d_in[4 + i];
    const float* fc1w = (const float*)d_in[28];
    const float* fc1b = (const float*)d_in[29];
    const float* fc2w = (const float*)d_in[30];
    const float* fc2b = (const float*)d_in[31];

    // workspace layout (same footprint as round 2)
    float* hA  = (float*)d_ws;                 // N*64 f32
    float* hB  = hA + (size_t)N * 64;          // N*64 f32
    short* zgb = (short*)(hB + (size_t)N * 64);// 64*E bf16
    short* xbA = zgb + (size_t)64 * E;         // N*64 bf16
    short* xbB = xbA + (size_t)N * 64;         // N*64 bf16
    short* w2t = xbB + (size_t)N * 64;         // 65*64*64 bf16 (reused per layer)

    int ebl   = (E + 63) / 64;      // edge-mlp tiles (64 edges)
    int mbl   = (E + 127) / 128;    // msg tiles (128 edges)
    int n64   = (N * 64 + 255) / 256;
    int nln   = (N + 3) / 4;
    int pw64  = (65 * 64 * 64 + 255) / 256;
    int pw32  = (65 * 64 * 32 + 255) / 256;

    k_cvt<<<(N * 32 + 255) / 256, 256, 0, stream>>>(x, xbA, N * 32);

    // ---- layer 1 (cin = 32) ----
    k_prep_w2<32><<<pw32, 256, 0, stream>>>(P[2], P[3], w2t);
    k_edge_mlp<<<ebl, 256, 0, stream>>>(ea, P[0], P[1], zgb, E);
    k_root<32><<<n64, 256, 0, stream>>>(x, P[4], P[5], hA, N);
    k_msg<32><<<mbl, 512, 0, stream>>>(zgb, xbA, src, dstv, w2t, hA, E);
    k_ln<<<nln, 256, 0, stream>>>(hA, P[6], P[7], xbB, N);

    // ---- layer 2 (cin = 64) ----
    k_prep_w2<64><<<pw64, 256, 0, stream>>>(P[10], P[11], w2t);
    k_edge_mlp<<<ebl, 256, 0, stream>>>(ea, P[8], P[9], zgb, E);
    k_root<64><<<n64, 256, 0, stream>>>(hA, P[12], P[13], hB, N);
    k_msg<64><<<mbl, 512, 0, stream>>>(zgb, xbB, src, dstv, w2t, hB, E);
    k_ln<<<nln, 256, 0, stream>>>(hB, P[14], P[15], xbA, N);

    // ---- layer 3 (cin = 64) ----
    k_prep_w2<64><<<pw64, 256, 0, stream>>>(P[18], P[19], w2t);
    k_edge_mlp<<<ebl, 256, 0, stream>>>(ea, P[16], P[17], zgb, E);
    k_root<64><<<n64, 256, 0, stream>>>(hB, P[20], P[21], hA, N);
    k_msg<64><<<mbl, 512, 0, stream>>>(zgb, xbA, src, dstv, w2t, hA, E);
    k_ln<<<nln, 256, 0, stream>>>(hA, P[22], P[23], xbB, N);

    // ---- fused pool + head ----
    k_pool_head<<<G, 256, 0, stream>>>(hA, batch, fc1w, fc1b, fc2w, fc2b, (float*)d_out, N);
}

// Round 4
// 466.893 us; speedup vs baseline: 1.4319x; 1.4319x over previous
//
#include <hip/hip_runtime.h>
#include <hip/hip_bf16.h>

#define EPSV 1e-5f

typedef __attribute__((ext_vector_type(8))) short bf16x8;
typedef __attribute__((ext_vector_type(16))) float f32x16;

static __device__ __forceinline__ short f2bf(float f) {
    __hip_bfloat16 b = __float2bfloat16(f);
    return __builtin_bit_cast(short, b);
}
static __device__ __forceinline__ float bf2f(short s) {
    unsigned u = ((unsigned)(unsigned short)s) << 16;
    return __builtin_bit_cast(float, u);
}

// f32 -> bf16 bulk convert
__global__ void k_cvt(const float* __restrict__ x, short* __restrict__ xb, int n) {
    int i = blockIdx.x * blockDim.x + threadIdx.x;
    if (i < n) xb[i] = f2bf(x[i]);
}

// w2t[h][o][i] = bf16(w2[h][i*64+o]) for h<64 ; b2[i*64+o] for h==64
template <int CIN>
__global__ void k_prep_w2(const float* __restrict__ w2, const float* __restrict__ b2,
                          short* __restrict__ w2t) {
    int idx = blockIdx.x * blockDim.x + threadIdx.x;
    int total = 65 * 64 * CIN;
    if (idx >= total) return;
    int i = idx % CIN;
    int rest = idx / CIN;
    int o = rest & 63;
    int h = rest >> 6;
    float v = (h < 64) ? w2[(size_t)h * (CIN * 64) + i * 64 + o] : b2[i * 64 + o];
    w2t[idx] = f2bf(v);
}

// zge[e][h] (row stride 80, 16B-aligned) = bf16(relu(b1[h] + sum_i ea[e*16+i]*w1[i*64+h]))
__global__ void k_edge_mlp(const float* __restrict__ ea, const float* __restrict__ w1,
                           const float* __restrict__ b1, short* __restrict__ zge, int E) {
    __shared__ float sEA[64][17];
    int t = threadIdx.x;
    int e0 = blockIdx.x * 64;
    for (int f = t; f < 64 * 16; f += 256) {
        int e = f >> 4, i = f & 15;
        int ge = e0 + e;
        sEA[e][i] = (ge < E) ? ea[(size_t)ge * 16 + i] : 0.f;
    }
    __syncthreads();
    int lane = t & 63, w = t >> 6;
    int ge = e0 + lane;
    union { bf16x8 v[2]; short s[16]; } ov;
    #pragma unroll
    for (int hh = 0; hh < 16; ++hh) {
        int h = w * 16 + hh;
        float acc = b1[h];
        #pragma unroll
        for (int i = 0; i < 16; ++i) acc += sEA[lane][i] * w1[i * 64 + h];
        ov.s[hh] = f2bf(fmaxf(acc, 0.f));
    }
    if (ge < E) {
        short* base = zge + (size_t)ge * 80 + w * 16;
        *reinterpret_cast<bf16x8*>(base) = ov.v[0];
        *reinterpret_cast<bf16x8*>(base + 8) = ov.v[1];
    }
}

// out[n*64+o] = bias[o] + sum_i hin[n*CIN+i] * root[i*64+o]   (inits agg)
template <int CIN>
__global__ void k_root(const float* __restrict__ hin, const float* __restrict__ root,
                       const float* __restrict__ bias, float* __restrict__ out, int N) {
    int idx = blockIdx.x * blockDim.x + threadIdx.x;
    int n = idx >> 6, o = idx & 63;
    if (n >= N) return;
    float acc = bias[o];
    #pragma unroll
    for (int i = 0; i < CIN; ++i) acc += hin[(size_t)n * CIN + i] * root[i * 64 + o];
    out[(size_t)n * 64 + o] = acc;
}

// MFMA msg v3: A = W2_h^T (o x i) streamed from L2, B = x^T fixed in regs,
// z per-lane in regs, zero-C MFMA chains, LDS-transpose epilogue -> coalesced atomics.
template <int CIN>
__global__ __launch_bounds__(256, 3) void k_msg(const short* __restrict__ zge,
                                                const short* __restrict__ xb,
                                                const int* __restrict__ src,
                                                const int* __restrict__ dstv,
                                                const short* __restrict__ w2t,
                                                float* __restrict__ agg, int E) {
    constexpr int CH = CIN / 16;
    __shared__ float sT[64][66];
    int t = threadIdx.x;
    int e0 = blockIdx.x * 64;
    int lane = t & 63, w = t >> 6;
    int rowg = w >> 1;            // o half
    int colg = w & 1;             // e half
    int kg = lane >> 5, l31 = lane & 31;
    int orow = rowg * 32 + l31;
    int ecol = colg * 32 + l31;
    int ge = e0 + ecol;
    int gec = min(ge, E - 1);

    // B operand: x[src(e)] fragments, fixed across all h
    int srow = src[gec];
    bf16x8 xB[CH];
    #pragma unroll
    for (int c = 0; c < CH; ++c)
        xB[c] = *reinterpret_cast<const bf16x8*>(xb + (size_t)srow * CIN + c * 16 + kg * 8);

    // z for this lane's edge: 64 bf16 in 8 vectors (32 packed u32 pairs)
    union { bf16x8 v[8]; unsigned u[32]; } zr;
    {
        const short* zb = zge + (size_t)gec * 80;
        #pragma unroll
        for (int c = 0; c < 8; ++c)
            zr.v[c] = *reinterpret_cast<const bf16x8*>(zb + c * 8);
    }

    f32x16 zero;
    #pragma unroll
    for (int r = 0; r < 16; ++r) zero[r] = 0.f;
    asm volatile("" : "+v"(zero));   // keep an opaque zero reg-tuple: no per-iter v_mov

    f32x16 acc = zero;
    const short* ap = w2t + (size_t)orow * CIN + kg * 8;

    #pragma unroll 2
    for (int hp = 0; hp < 32; ++hp) {
        bf16x8 a0[CH], a1[CH];
        #pragma unroll
        for (int c = 0; c < CH; ++c) {
            a0[c] = *reinterpret_cast<const bf16x8*>(ap + (size_t)(2 * hp) * (64 * CIN) + c * 16);
            a1[c] = *reinterpret_cast<const bf16x8*>(ap + (size_t)(2 * hp + 1) * (64 * CIN) + c * 16);
        }
        unsigned zp = zr.u[hp];
        float zlo = __builtin_bit_cast(float, zp << 16);
        float zhi = __builtin_bit_cast(float, zp & 0xffff0000u);
        f32x16 t0 = __builtin_amdgcn_mfma_f32_32x32x16_bf16(a0[0], xB[0], zero, 0, 0, 0);
        f32x16 t1 = __builtin_amdgcn_mfma_f32_32x32x16_bf16(a1[0], xB[0], zero, 0, 0, 0);
        #pragma unroll
        for (int c = 1; c < CH; ++c) {
            t0 = __builtin_amdgcn_mfma_f32_32x32x16_bf16(a0[c], xB[c], t0, 0, 0, 0);
            t1 = __builtin_amdgcn_mfma_f32_32x32x16_bf16(a1[c], xB[c], t1, 0, 0, 0);
        }
        #pragma unroll
        for (int r = 0; r < 16; ++r) {
            acc[r] = fmaf(zlo, t0[r], acc[r]);
            acc[r] = fmaf(zhi, t1[r], acc[r]);
        }
    }
    {   // h == 64: b2 term (z = 1)
        f32x16 tb = __builtin_amdgcn_mfma_f32_32x32x16_bf16(
            *reinterpret_cast<const bf16x8*>(ap + (size_t)64 * (64 * CIN)), xB[0], zero, 0, 0, 0);
        #pragma unroll
        for (int c = 1; c < CH; ++c)
            tb = __builtin_amdgcn_mfma_f32_32x32x16_bf16(
                *reinterpret_cast<const bf16x8*>(ap + (size_t)64 * (64 * CIN) + c * 16), xB[c], tb, 0, 0, 0);
        #pragma unroll
        for (int r = 0; r < 16; ++r) acc[r] += tb[r];
    }

    // transpose via LDS: D[row=o][col=e] -> sT, each wave writes a disjoint 32x32 quadrant
    #pragma unroll
    for (int r = 0; r < 16; ++r) {
        int o = (r & 3) + 8 * (r >> 2) + 4 * kg + 32 * rowg;
        sT[o][ecol] = acc[r];
    }
    __syncthreads();

    // coalesced scatter: 64 lanes = 64 consecutive o for one edge
    for (int e = w; e < 64; e += 4) {
        int geo = e0 + e;
        if (geo < E) {
            int d = dstv[geo];
            atomicAdd(&agg[(size_t)d * 64 + lane], sT[lane][e]);
        }
    }
}

// in-place LayerNorm + ReLU; also emits bf16 copy for next layer's MFMA input
__global__ void k_ln(float* __restrict__ h, const float* __restrict__ g, const float* __restrict__ b,
                     short* __restrict__ hb, int N) {
    int n = blockIdx.x * 4 + (threadIdx.x >> 6);
    int lane = threadIdx.x & 63;
    if (n >= N) return;
    float v = h[(size_t)n * 64 + lane];
    float s = v;
    #pragma unroll
    for (int d = 32; d > 0; d >>= 1) s += __shfl_xor(s, d, 64);
    float mean = s * (1.f / 64.f);
    float dv = v - mean;
    float s2 = dv * dv;
    #pragma unroll
    for (int d = 32; d > 0; d >>= 1) s2 += __shfl_xor(s2, d, 64);
    float var = s2 * (1.f / 64.f);
    float o = fmaxf(dv * rsqrtf(var + EPSV) * g[lane] + b[lane], 0.f);
    h[(size_t)n * 64 + lane] = o;
    hb[(size_t)n * 64 + lane] = f2bf(o);
}

// fused mean-pool (binary search on sorted batch) + MLP head; 4 waves/graph
__global__ void k_pool_head(const float* __restrict__ h, const int* __restrict__ batch,
                            const float* __restrict__ fc1w, const float* __restrict__ fc1b,
                            const float* __restrict__ fc2w, const float* __restrict__ fc2b,
                            float* __restrict__ out, int N) {
    __shared__ float part[4][64];
    __shared__ float sh[64];
    __shared__ float sh2[32];
    int g = blockIdx.x;
    int t = threadIdx.x, lane = t & 63, w = t >> 6;
    int lo = 0, hi = N;
    while (lo < hi) { int m = (lo + hi) >> 1; if (batch[m] < g) lo = m + 1; else hi = m; }
    int s0 = lo;
    hi = N;
    while (lo < hi) { int m = (lo + hi) >> 1; if (batch[m] < g + 1) lo = m + 1; else hi = m; }
    int s1 = lo;
    float s = 0.f;
    for (int n = s0 + w; n < s1; n += 4) s += h[(size_t)n * 64 + lane];
    part[w][lane] = s;
    __syncthreads();
    if (t < 64) {
        float c = fmaxf((float)(s1 - s0), 1.f);
        sh[t] = (part[0][t] + part[1][t] + part[2][t] + part[3][t]) / c;
    }
    __syncthreads();
    if (t < 32) {
        float a = fc1b[t];
        #pragma unroll
        for (int o = 0; o < 64; ++o) a += sh[o] * fc1w[o * 32 + t];
        sh2[t] = fmaxf(a, 0.f);
    }
    __syncthreads();
    if (t == 0) {
        float a = fc2b[0];
        #pragma unroll
        for (int j = 0; j < 32; ++j) a += sh2[j] * fc2w[j];
        out[g] = a;
    }
}

extern "C" void kernel_launch(void* const* d_in, const int* in_sizes, int n_in,
                              void* d_out, int out_size, void* d_ws, size_t ws_size,
                              hipStream_t stream) {
    const float* x     = (const float*)d_in[0];
    const int*   ei    = (const int*)d_in[1];
    const float* ea    = (const float*)d_in[2];
    const int*   batch = (const int*)d_in[3];
    int E = in_sizes[1] / 2;
    int N = in_sizes[3];
    int G = out_size;  // DOUT = 1
    const int* src  = ei;
    const int* dstv = ei + E;

    const float* P[24];
    for (int i = 0; i < 24; ++i) P[i] = (const float*)d_in[4 + i];
    const float* fc1w = (const float*)d_in[28];
    const float* fc1b = (const float*)d_in[29];
    const float* fc2w = (const float*)d_in[30];
    const float* fc2b = (const float*)d_in[31];

    // workspace layout
    float* hA  = (float*)d_ws;                 // N*64 f32
    float* hB  = hA + (size_t)N * 64;          // N*64 f32
    short* zge = (short*)(hB + (size_t)N * 64);// E*80 bf16 (z rows, padded)
    short* xbA = zge + (size_t)E * 80;         // N*64 bf16
    short* xbB = xbA + (size_t)N * 64;         // N*64 bf16
    short* w2t = xbB + (size_t)N * 64;         // 65*64*64 bf16 (reused per layer)

    int ebl   = (E + 63) / 64;
    int n64   = (N * 64 + 255) / 256;
    int nln   = (N + 3) / 4;
    int pw64  = (65 * 64 * 64 + 255) / 256;
    int pw32  = (65 * 64 * 32 + 255) / 256;

    k_cvt<<<(N * 32 + 255) / 256, 256, 0, stream>>>(x, xbA, N * 32);

    // ---- layer 1 (cin = 32) ----
    k_prep_w2<32><<<pw32, 256, 0, stream>>>(P[2], P[3], w2t);
    k_edge_mlp<<<ebl, 256, 0, stream>>>(ea, P[0], P[1], zge, E);
    k_root<32><<<n64, 256, 0, stream>>>(x, P[4], P[5], hA, N);
    k_msg<32><<<ebl, 256, 0, stream>>>(zge, xbA, src, dstv, w2t, hA, E);
    k_ln<<<nln, 256, 0, stream>>>(hA, P[6], P[7], xbB, N);

    // ---- layer 2 (cin = 64) ----
    k_prep_w2<64><<<pw64, 256, 0, stream>>>(P[10], P[11], w2t);
    k_edge_mlp<<<ebl, 256, 0, stream>>>(ea, P[8], P[9], zge, E);
    k_root<64><<<n64, 256, 0, stream>>>(hA, P[12], P[13], hB, N);
    k_msg<64><<<ebl, 256, 0, stream>>>(zge, xbB, src, dstv, w2t, hB, E);
    k_ln<<<nln, 256, 0, stream>>>(hB, P[14], P[15], xbA, N);

    // ---- layer 3 (cin = 64) ----
    k_prep_w2<64><<<pw64, 256, 0, stream>>>(P[18], P[19], w2t);
    k_edge_mlp<<<ebl, 256, 0, stream>>>(ea, P[16], P[17], zge, E);
    k_root<64><<<n64, 256, 0, stream>>>(hB, P[20], P[21], hA, N);
    k_msg<64><<<ebl, 256, 0, stream>>>(zge, xbA, src, dstv, w2t, hA, E);
    k_ln<<<nln, 256, 0, stream>>>(hA, P[22], P[23], xbB, N);

    // ---- fused pool + head ----
    k_pool_head<<<G, 256, 0, stream>>>(hA, batch, fc1w, fc1b, fc2w, fc2b, (float*)d_out, N);
}

// Round 5
// 334.783 us; speedup vs baseline: 1.9970x; 1.3946x over previous
//
#include <hip/hip_runtime.h>
#include <hip/hip_bf16.h>

#define EPSV 1e-5f

typedef __attribute__((ext_vector_type(8))) short bf16x8;
typedef __attribute__((ext_vector_type(16))) float f32x16;

static __device__ __forceinline__ short f2bf(float f) {
    __hip_bfloat16 b = __float2bfloat16(f);
    return __builtin_bit_cast(short, b);
}

// f32 -> bf16 bulk convert
__global__ void k_cvt(const float* __restrict__ x, short* __restrict__ xb, int n) {
    int i = blockIdx.x * blockDim.x + threadIdx.x;
    if (i < n) xb[i] = f2bf(x[i]);
}

// Fragment-ordered weights: w2a[((h*CH + c)*2 + rowg)*512 + lane*8 + j]
//   = bf16( w2[h][i*64+o] ), o = rowg*32 + (lane&31), i = c*16 + (lane>>5)*8 + j
// h==64 slab holds b2. A wave's fragment load = contiguous 1KB.
template <int CIN>
__global__ void k_prep_w2(const float* __restrict__ w2, const float* __restrict__ b2,
                          short* __restrict__ w2a) {
    constexpr int CH = CIN / 16;
    int idx = blockIdx.x * blockDim.x + threadIdx.x;
    int total = 65 * CH * 2 * 512;
    if (idx >= total) return;
    int j = idx & 7;
    int l = (idx >> 3) & 63;
    int rowg = (idx >> 9) & 1;
    int c = (idx >> 10) % CH;
    int h = idx / (CH * 1024);
    int o = rowg * 32 + (l & 31);
    int i = c * 16 + (l >> 5) * 8 + j;
    float v = (h < 64) ? w2[(size_t)h * (CIN * 64) + i * 64 + o] : b2[i * 64 + o];
    w2a[idx] = f2bf(v);
}

// z rows, h-half-major: zge[(hb*E + e)*32 + hh] = bf16(relu(b1[h]+ea@w1)), h = hb*32+hh
__global__ void k_edge_mlp(const float* __restrict__ ea, const float* __restrict__ w1,
                           const float* __restrict__ b1, short* __restrict__ zge, int E) {
    __shared__ float sEA[64][17];
    int t = threadIdx.x;
    int e0 = blockIdx.x * 64;
    for (int f = t; f < 64 * 16; f += 256) {
        int e = f >> 4, i = f & 15;
        int ge = e0 + e;
        sEA[e][i] = (ge < E) ? ea[(size_t)ge * 16 + i] : 0.f;
    }
    __syncthreads();
    int lane = t & 63, w = t >> 6;
    int ge = e0 + lane;
    union { bf16x8 v[2]; short s[16]; } ov;
    #pragma unroll
    for (int hh = 0; hh < 16; ++hh) {
        int h = w * 16 + hh;
        float acc = b1[h];
        #pragma unroll
        for (int i = 0; i < 16; ++i) acc += sEA[lane][i] * w1[i * 64 + h];
        ov.s[hh] = f2bf(fmaxf(acc, 0.f));
    }
    if (ge < E) {
        short* base = zge + ((size_t)(w >> 1) * E + ge) * 32 + (w & 1) * 16;
        *reinterpret_cast<bf16x8*>(base) = ov.v[0];
        *reinterpret_cast<bf16x8*>(base + 8) = ov.v[1];
    }
}

// out[n*64+o] = bias[o] + sum_i hin[n*CIN+i] * root[i*64+o]   (inits agg)
template <int CIN>
__global__ void k_root(const float* __restrict__ hin, const float* __restrict__ root,
                       const float* __restrict__ bias, float* __restrict__ out, int N) {
    int idx = blockIdx.x * blockDim.x + threadIdx.x;
    int n = idx >> 6, o = idx & 63;
    if (n >= N) return;
    float acc = bias[o];
    #pragma unroll
    for (int i = 0; i < CIN; ++i) acc += hin[(size_t)n * CIN + i] * root[i * 64 + o];
    out[(size_t)n * 64 + o] = acc;
}

// MFMA msg v4: coalesced fragment loads from w2a; h-range split across block pairs
// (blockIdx = tile*2 + hb, hb handles h in [hb*32, hb*32+32) (+b2 slab for hb=1)).
// LDS-transpose epilogue -> coalesced atomic scatter (partial sums merge in agg).
template <int CIN>
__global__ __launch_bounds__(256, 4) void k_msg(const short* __restrict__ zge,
                                                const short* __restrict__ xb,
                                                const int* __restrict__ src,
                                                const int* __restrict__ dstv,
                                                const short* __restrict__ w2a,
                                                float* __restrict__ agg, int E) {
    constexpr int CH = CIN / 16;
    __shared__ float sT[64][66];
    int t = threadIdx.x;
    int tile = blockIdx.x >> 1, hb = blockIdx.x & 1;
    int e0 = tile * 64;
    int lane = t & 63, w = t >> 6;
    int rowg = w >> 1;            // o half
    int colg = w & 1;             // e half
    int kg = lane >> 5, l31 = lane & 31;
    int ecol = colg * 32 + l31;
    int ge = e0 + ecol;
    int gec = min(ge, E - 1);

    // B operand: x[src(e)] fragments, fixed across all h
    int srow = src[gec];
    bf16x8 xB[CH];
    #pragma unroll
    for (int c = 0; c < CH; ++c)
        xB[c] = *reinterpret_cast<const bf16x8*>(xb + (size_t)srow * CIN + c * 16 + kg * 8);

    // z for this lane's edge, this block's h-half: 32 bf16 = 16 packed pairs (coalesced 64B)
    union { bf16x8 v[4]; unsigned u[16]; } zr;
    {
        const short* zb = zge + ((size_t)hb * E + gec) * 32;
        #pragma unroll
        for (int c = 0; c < 4; ++c)
            zr.v[c] = *reinterpret_cast<const bf16x8*>(zb + c * 8);
    }

    f32x16 zero;
    #pragma unroll
    for (int r = 0; r < 16; ++r) zero[r] = 0.f;
    asm volatile("" : "+v"(zero));   // opaque zero tuple: no per-iter v_mov

    f32x16 acc = zero;
    const short* ap = w2a + rowg * 512 + lane * 8;
    const int hbase = hb * 32;

    #pragma unroll 1
    for (int hp = 0; hp < 16; ++hp) {
        int h0 = hbase + 2 * hp;
        bf16x8 a0[CH], a1[CH];
        #pragma unroll
        for (int c = 0; c < CH; ++c) {
            a0[c] = *reinterpret_cast<const bf16x8*>(ap + (size_t)(h0 * CH + c) * 1024);
            a1[c] = *reinterpret_cast<const bf16x8*>(ap + (size_t)((h0 + 1) * CH + c) * 1024);
        }
        unsigned zp = zr.u[hp];
        float zlo = __builtin_bit_cast(float, zp << 16);
        float zhi = __builtin_bit_cast(float, zp & 0xffff0000u);
        f32x16 t0 = __builtin_amdgcn_mfma_f32_32x32x16_bf16(a0[0], xB[0], zero, 0, 0, 0);
        f32x16 t1 = __builtin_amdgcn_mfma_f32_32x32x16_bf16(a1[0], xB[0], zero, 0, 0, 0);
        #pragma unroll
        for (int c = 1; c < CH; ++c) {
            t0 = __builtin_amdgcn_mfma_f32_32x32x16_bf16(a0[c], xB[c], t0, 0, 0, 0);
            t1 = __builtin_amdgcn_mfma_f32_32x32x16_bf16(a1[c], xB[c], t1, 0, 0, 0);
        }
        #pragma unroll
        for (int r = 0; r < 16; ++r) {
            acc[r] = fmaf(zlo, t0[r], acc[r]);
            acc[r] = fmaf(zhi, t1[r], acc[r]);
        }
    }
    if (hb) {   // b2 slab (z = 1)
        f32x16 tb = __builtin_amdgcn_mfma_f32_32x32x16_bf16(
            *reinterpret_cast<const bf16x8*>(ap + (size_t)(64 * CH) * 1024), xB[0], zero, 0, 0, 0);
        #pragma unroll
        for (int c = 1; c < CH; ++c)
            tb = __builtin_amdgcn_mfma_f32_32x32x16_bf16(
                *reinterpret_cast<const bf16x8*>(ap + (size_t)(64 * CH + c) * 1024), xB[c], tb, 0, 0, 0);
        #pragma unroll
        for (int r = 0; r < 16; ++r) acc[r] += tb[r];
    }

    // transpose via LDS: each wave writes a disjoint 32x32 quadrant
    #pragma unroll
    for (int r = 0; r < 16; ++r) {
        int o = (r & 3) + 8 * (r >> 2) + 4 * kg + 32 * rowg;
        sT[o][ecol] = acc[r];
    }
    __syncthreads();

    // coalesced scatter: 64 lanes = 64 consecutive o for one edge
    for (int e = w; e < 64; e += 4) {
        int geo = e0 + e;
        if (geo < E) {
            int d = dstv[geo];
            atomicAdd(&agg[(size_t)d * 64 + lane], sT[lane][e]);
        }
    }
}

// in-place LayerNorm + ReLU; also emits bf16 copy for next layer's MFMA input
__global__ void k_ln(float* __restrict__ h, const float* __restrict__ g, const float* __restrict__ b,
                     short* __restrict__ hb, int N) {
    int n = blockIdx.x * 4 + (threadIdx.x >> 6);
    int lane = threadIdx.x & 63;
    if (n >= N) return;
    float v = h[(size_t)n * 64 + lane];
    float s = v;
    #pragma unroll
    for (int d = 32; d > 0; d >>= 1) s += __shfl_xor(s, d, 64);
    float mean = s * (1.f / 64.f);
    float dv = v - mean;
    float s2 = dv * dv;
    #pragma unroll
    for (int d = 32; d > 0; d >>= 1) s2 += __shfl_xor(s2, d, 64);
    float var = s2 * (1.f / 64.f);
    float o = fmaxf(dv * rsqrtf(var + EPSV) * g[lane] + b[lane], 0.f);
    h[(size_t)n * 64 + lane] = o;
    hb[(size_t)n * 64 + lane] = f2bf(o);
}

// fused mean-pool (binary search on sorted batch) + MLP head; 4 waves/graph
__global__ void k_pool_head(const float* __restrict__ h, const int* __restrict__ batch,
                            const float* __restrict__ fc1w, const float* __restrict__ fc1b,
                            const float* __restrict__ fc2w, const float* __restrict__ fc2b,
                            float* __restrict__ out, int N) {
    __shared__ float part[4][64];
    __shared__ float sh[64];
    __shared__ float sh2[32];
    int g = blockIdx.x;
    int t = threadIdx.x, lane = t & 63, w = t >> 6;
    int lo = 0, hi = N;
    while (lo < hi) { int m = (lo + hi) >> 1; if (batch[m] < g) lo = m + 1; else hi = m; }
    int s0 = lo;
    hi = N;
    while (lo < hi) { int m = (lo + hi) >> 1; if (batch[m] < g + 1) lo = m + 1; else hi = m; }
    int s1 = lo;
    float s = 0.f;
    for (int n = s0 + w; n < s1; n += 4) s += h[(size_t)n * 64 + lane];
    part[w][lane] = s;
    __syncthreads();
    if (t < 64) {
        float c = fmaxf((float)(s1 - s0), 1.f);
        sh[t] = (part[0][t] + part[1][t] + part[2][t] + part[3][t]) / c;
    }
    __syncthreads();
    if (t < 32) {
        float a = fc1b[t];
        #pragma unroll
        for (int o = 0; o < 64; ++o) a += sh[o] * fc1w[o * 32 + t];
        sh2[t] = fmaxf(a, 0.f);
    }
    __syncthreads();
    if (t == 0) {
        float a = fc2b[0];
        #pragma unroll
        for (int j = 0; j < 32; ++j) a += sh2[j] * fc2w[j];
        out[g] = a;
    }
}

extern "C" void kernel_launch(void* const* d_in, const int* in_sizes, int n_in,
                              void* d_out, int out_size, void* d_ws, size_t ws_size,
                              hipStream_t stream) {
    const float* x     = (const float*)d_in[0];
    const int*   ei    = (const int*)d_in[1];
    const float* ea    = (const float*)d_in[2];
    const int*   batch = (const int*)d_in[3];
    int E = in_sizes[1] / 2;
    int N = in_sizes[3];
    int G = out_size;  // DOUT = 1
    const int* src  = ei;
    const int* dstv = ei + E;

    const float* P[24];
    for (int i = 0; i < 24; ++i) P[i] = (const float*)d_in[4 + i];
    const float* fc1w = (const float*)d_in[28];
    const float* fc1b = (const float*)d_in[29];
    const float* fc2w = (const float*)d_in[30];
    const float* fc2b = (const float*)d_in[31];

    // workspace layout
    float* hA  = (float*)d_ws;                 // N*64 f32
    float* hB  = hA + (size_t)N * 64;          // N*64 f32
    short* zge = (short*)(hB + (size_t)N * 64);// E*64 bf16 (z rows, h-half-major)
    short* xbA = zge + (size_t)E * 64;         // N*64 bf16
    short* xbB = xbA + (size_t)N * 64;         // N*64 bf16
    short* w2a = xbB + (size_t)N * 64;         // 65*64*64 bf16, fragment-ordered

    int ebl   = (E + 63) / 64;
    int mbl   = ebl * 2;                       // h-split pairs
    int n64   = (N * 64 + 255) / 256;
    int nln   = (N + 3) / 4;
    int pw64  = (65 * 4 * 2 * 512 + 255) / 256;
    int pw32  = (65 * 2 * 2 * 512 + 255) / 256;

    k_cvt<<<(N * 32 + 255) / 256, 256, 0, stream>>>(x, xbA, N * 32);

    // ---- layer 1 (cin = 32) ----
    k_prep_w2<32><<<pw32, 256, 0, stream>>>(P[2], P[3], w2a);
    k_edge_mlp<<<ebl, 256, 0, stream>>>(ea, P[0], P[1], zge, E);
    k_root<32><<<n64, 256, 0, stream>>>(x, P[4], P[5], hA, N);
    k_msg<32><<<mbl, 256, 0, stream>>>(zge, xbA, src, dstv, w2a, hA, E);
    k_ln<<<nln, 256, 0, stream>>>(hA, P[6], P[7], xbB, N);

    // ---- layer 2 (cin = 64) ----
    k_prep_w2<64><<<pw64, 256, 0, stream>>>(P[10], P[11], w2a);
    k_edge_mlp<<<ebl, 256, 0, stream>>>(ea, P[8], P[9], zge, E);
    k_root<64><<<n64, 256, 0, stream>>>(hA, P[12], P[13], hB, N);
    k_msg<64><<<mbl, 256, 0, stream>>>(zge, xbB, src, dstv, w2a, hB, E);
    k_ln<<<nln, 256, 0, stream>>>(hB, P[14], P[15], xbA, N);

    // ---- layer 3 (cin = 64) ----
    k_prep_w2<64><<<pw64, 256, 0, stream>>>(P[18], P[19], w2a);
    k_edge_mlp<<<ebl, 256, 0, stream>>>(ea, P[16], P[17], zge, E);
    k_root<64><<<n64, 256, 0, stream>>>(hB, P[20], P[21], hA, N);
    k_msg<64><<<mbl, 256, 0, stream>>>(zge, xbA, src, dstv, w2a, hA, E);
    k_ln<<<nln, 256, 0, stream>>>(hA, P[22], P[23], xbB, N);

    // ---- fused pool + head ----
    k_pool_head<<<G, 256, 0, stream>>>(hA, batch, fc1w, fc1b, fc2w, fc2b, (float*)d_out, N);
}

// Round 6
// 282.820 us; speedup vs baseline: 2.3639x; 1.1837x over previous
//
#include <hip/hip_runtime.h>
#include <hip/hip_bf16.h>

#define EPSV 1e-5f

typedef __attribute__((ext_vector_type(8))) short bf16x8;
typedef __attribute__((ext_vector_type(16))) float f32x16;

static __device__ __forceinline__ short f2bf(float f) {
    __hip_bfloat16 b = __float2bfloat16(f);
    return __builtin_bit_cast(short, b);
}

// f32 -> bf16 bulk convert
__global__ void k_cvt(const float* __restrict__ x, short* __restrict__ xb, int n) {
    int i = blockIdx.x * blockDim.x + threadIdx.x;
    if (i < n) xb[i] = f2bf(x[i]);
}

// Fused: blocks [0, EBL) run the edge MLP (z generation); blocks [EBL, ...) repack w2 -> w2a.
// w2a[((h*CH + c)*2 + rowg)*512 + lane*8 + j] = bf16(w2[h][i*64+o]),
//   o = rowg*32 + (lane&31), i = c*16 + (lane>>5)*8 + j ; h==64 slab holds b2.
// zge[(hb*E + e)*32 + (h - hb*32)] = bf16(relu(b1[h] + ea@w1))
template <int CIN>
__global__ void k_edge_prep(const float* __restrict__ ea, const float* __restrict__ w1,
                            const float* __restrict__ b1, short* __restrict__ zge, int E, int EBL,
                            const float* __restrict__ w2, const float* __restrict__ b2,
                            short* __restrict__ w2a) {
    constexpr int CH = CIN / 16;
    int t = threadIdx.x;
    if ((int)blockIdx.x >= EBL) {
        int idx = ((int)blockIdx.x - EBL) * 256 + t;
        int total = 65 * CH * 2 * 512;
        if (idx >= total) return;
        int j = idx & 7;
        int l = (idx >> 3) & 63;
        int rowg = (idx >> 9) & 1;
        int c = (idx >> 10) % CH;
        int h = idx / (CH * 1024);
        int o = rowg * 32 + (l & 31);
        int i = c * 16 + (l >> 5) * 8 + j;
        float v = (h < 64) ? w2[(size_t)h * (CIN * 64) + i * 64 + o] : b2[i * 64 + o];
        w2a[idx] = f2bf(v);
        return;
    }
    __shared__ float sEA[64][17];
    int e0 = blockIdx.x * 64;
    for (int f = t; f < 64 * 16; f += 256) {
        int e = f >> 4, i = f & 15;
        int ge = e0 + e;
        sEA[e][i] = (ge < E) ? ea[(size_t)ge * 16 + i] : 0.f;
    }
    __syncthreads();
    int lane = t & 63, w = t >> 6;
    int ge = e0 + lane;
    union { bf16x8 v[2]; short s[16]; } ov;
    #pragma unroll
    for (int hh = 0; hh < 16; ++hh) {
        int h = w * 16 + hh;
        float acc = b1[h];
        #pragma unroll
        for (int i = 0; i < 16; ++i) acc += sEA[lane][i] * w1[i * 64 + h];
        ov.s[hh] = f2bf(fmaxf(acc, 0.f));
    }
    if (ge < E) {
        short* base = zge + ((size_t)(w >> 1) * E + ge) * 32 + (w & 1) * 16;
        *reinterpret_cast<bf16x8*>(base) = ov.v[0];
        *reinterpret_cast<bf16x8*>(base + 8) = ov.v[1];
    }
}

// layer-1 agg init: out[n*64+o] = bias[o] + sum_i x[n*32+i]*root[i*64+o]
__global__ void k_root32(const float* __restrict__ hin, const float* __restrict__ root,
                         const float* __restrict__ bias, float* __restrict__ out, int N) {
    int idx = blockIdx.x * blockDim.x + threadIdx.x;
    int n = idx >> 6, o = idx & 63;
    if (n >= N) return;
    float acc = bias[o];
    #pragma unroll
    for (int i = 0; i < 32; ++i) acc += hin[(size_t)n * 32 + i] * root[i * 64 + o];
    out[(size_t)n * 64 + o] = acc;
}

// MFMA msg v5: coalesced fragment loads, register double-buffered (software pipeline).
// blockIdx = tile*2 + hb; hb covers h in [hb*32, hb*32+32) (+b2 slab for hb=1).
template <int CIN>
__global__ __launch_bounds__(256, 3) void k_msg(const short* __restrict__ zge,
                                                const short* __restrict__ xb,
                                                const int* __restrict__ src,
                                                const int* __restrict__ dstv,
                                                const short* __restrict__ w2a,
                                                float* __restrict__ agg, int E) {
    constexpr int CH = CIN / 16;
    __shared__ float sT[64][66];
    int t = threadIdx.x;
    int tile = blockIdx.x >> 1, hb = blockIdx.x & 1;
    int e0 = tile * 64;
    int lane = t & 63, w = t >> 6;
    int rowg = w >> 1;            // o half
    int colg = w & 1;             // e half
    int kg = lane >> 5, l31 = lane & 31;
    int ecol = colg * 32 + l31;
    int ge = e0 + ecol;
    int gec = min(ge, E - 1);

    // B operand: x[src(e)] fragments, fixed across all h
    int srow = src[gec];
    bf16x8 xB[CH];
    #pragma unroll
    for (int c = 0; c < CH; ++c)
        xB[c] = *reinterpret_cast<const bf16x8*>(xb + (size_t)srow * CIN + c * 16 + kg * 8);

    // z for this lane's edge, this block's h-half: 32 bf16 (coalesced 64B)
    union { bf16x8 v[4]; unsigned u[16]; } zr;
    {
        const short* zb = zge + ((size_t)hb * E + gec) * 32;
        #pragma unroll
        for (int c = 0; c < 4; ++c)
            zr.v[c] = *reinterpret_cast<const bf16x8*>(zb + c * 8);
    }

    f32x16 zero;
    #pragma unroll
    for (int r = 0; r < 16; ++r) zero[r] = 0.f;
    asm volatile("" : "+v"(zero));   // opaque zero tuple: no per-iter v_mov

    f32x16 acc = zero;
    const short* ap = w2a + rowg * 512 + lane * 8;
    const int hbase = hb * 32;

    bf16x8 A0[2 * CH], A1[2 * CH];   // two h-pair slabs, static-indexed

    auto loadS = [&](bf16x8* B, int h0) {
        #pragma unroll
        for (int c = 0; c < CH; ++c) {
            B[c]      = *reinterpret_cast<const bf16x8*>(ap + (size_t)(h0 * CH + c) * 1024);
            B[CH + c] = *reinterpret_cast<const bf16x8*>(ap + (size_t)((h0 + 1) * CH + c) * 1024);
        }
    };
    auto consume = [&](const bf16x8* B, unsigned zp) {
        float zlo = __builtin_bit_cast(float, zp << 16);
        float zhi = __builtin_bit_cast(float, zp & 0xffff0000u);
        f32x16 t0 = __builtin_amdgcn_mfma_f32_32x32x16_bf16(B[0], xB[0], zero, 0, 0, 0);
        f32x16 t1 = __builtin_amdgcn_mfma_f32_32x32x16_bf16(B[CH], xB[0], zero, 0, 0, 0);
        #pragma unroll
        for (int c = 1; c < CH; ++c) {
            t0 = __builtin_amdgcn_mfma_f32_32x32x16_bf16(B[c], xB[c], t0, 0, 0, 0);
            t1 = __builtin_amdgcn_mfma_f32_32x32x16_bf16(B[CH + c], xB[c], t1, 0, 0, 0);
        }
        #pragma unroll
        for (int r = 0; r < 16; ++r) {
            acc[r] = fmaf(zlo, t0[r], acc[r]);
            acc[r] = fmaf(zhi, t1[r], acc[r]);
        }
    };

    loadS(A0, hbase);                       // prologue: slab for h-pair {0,1}
    #pragma unroll 1
    for (int hp = 0; hp < 8; ++hp) {        // each iter covers 4 h (2 pairs)
        loadS(A1, hbase + 4 * hp + 2);      // prefetch pair {4hp+2, 4hp+3}
        consume(A0, zr.u[2 * hp]);
        if (hp < 7) loadS(A0, hbase + 4 * hp + 4);  // prefetch pair {4hp+4, 4hp+5}
        consume(A1, zr.u[2 * hp + 1]);
    }
    if (hb) {   // b2 slab (z = 1)
        f32x16 tb = __builtin_amdgcn_mfma_f32_32x32x16_bf16(
            *reinterpret_cast<const bf16x8*>(ap + (size_t)(64 * CH) * 1024), xB[0], zero, 0, 0, 0);
        #pragma unroll
        for (int c = 1; c < CH; ++c)
            tb = __builtin_amdgcn_mfma_f32_32x32x16_bf16(
                *reinterpret_cast<const bf16x8*>(ap + (size_t)(64 * CH + c) * 1024), xB[c], tb, 0, 0, 0);
        #pragma unroll
        for (int r = 0; r < 16; ++r) acc[r] += tb[r];
    }

    // transpose via LDS: each wave writes a disjoint 32x32 quadrant
    #pragma unroll
    for (int r = 0; r < 16; ++r) {
        int o = (r & 3) + 8 * (r >> 2) + 4 * kg + 32 * rowg;
        sT[o][ecol] = acc[r];
    }
    __syncthreads();

    // coalesced scatter: 64 lanes = 64 consecutive o for one edge
    for (int e = w; e < 64; e += 4) {
        int geo = e0 + e;
        if (geo < E) {
            int d = dstv[geo];
            atomicAdd(&agg[(size_t)d * 64 + lane], sT[lane][e]);
        }
    }
}

// fused LayerNorm+ReLU -> bf16 (for next msg) AND next layer's root GEMM (agg init).
__global__ void k_ln_root(const float* __restrict__ hin, const float* __restrict__ g,
                          const float* __restrict__ b, const float* __restrict__ root,
                          const float* __restrict__ bias, short* __restrict__ xbout,
                          float* __restrict__ aggnext, int N) {
    __shared__ float sh[4][64];
    int w = threadIdx.x >> 6, lane = threadIdx.x & 63;
    int n = blockIdx.x * 4 + w;
    bool valid = n < N;
    int nc = valid ? n : (N - 1);
    float v = hin[(size_t)nc * 64 + lane];
    float s = v;
    #pragma unroll
    for (int d = 32; d > 0; d >>= 1) s += __shfl_xor(s, d, 64);
    float mean = s * (1.f / 64.f);
    float dv = v - mean;
    float s2 = dv * dv;
    #pragma unroll
    for (int d = 32; d > 0; d >>= 1) s2 += __shfl_xor(s2, d, 64);
    float var = s2 * (1.f / 64.f);
    float o = fmaxf(dv * rsqrtf(var + EPSV) * g[lane] + b[lane], 0.f);
    if (valid) xbout[(size_t)n * 64 + lane] = f2bf(o);
    sh[w][lane] = o;
    __syncthreads();
    float acc = bias[lane];
    #pragma unroll 8
    for (int i = 0; i < 64; ++i) acc = fmaf(sh[w][i], root[i * 64 + lane], acc);
    if (valid) aggnext[(size_t)n * 64 + lane] = acc;
}

// plain LayerNorm+ReLU in place (final layer)
__global__ void k_ln(float* __restrict__ h, const float* __restrict__ g, const float* __restrict__ b, int N) {
    int n = blockIdx.x * 4 + (threadIdx.x >> 6);
    int lane = threadIdx.x & 63;
    if (n >= N) return;
    float v = h[(size_t)n * 64 + lane];
    float s = v;
    #pragma unroll
    for (int d = 32; d > 0; d >>= 1) s += __shfl_xor(s, d, 64);
    float mean = s * (1.f / 64.f);
    float dv = v - mean;
    float s2 = dv * dv;
    #pragma unroll
    for (int d = 32; d > 0; d >>= 1) s2 += __shfl_xor(s2, d, 64);
    float var = s2 * (1.f / 64.f);
    h[(size_t)n * 64 + lane] = fmaxf(dv * rsqrtf(var + EPSV) * g[lane] + b[lane], 0.f);
}

// fused mean-pool (binary search on sorted batch) + MLP head; 4 waves/graph
__global__ void k_pool_head(const float* __restrict__ h, const int* __restrict__ batch,
                            const float* __restrict__ fc1w, const float* __restrict__ fc1b,
                            const float* __restrict__ fc2w, const float* __restrict__ fc2b,
                            float* __restrict__ out, int N) {
    __shared__ float part[4][64];
    __shared__ float sh[64];
    __shared__ float sh2[32];
    int g = blockIdx.x;
    int t = threadIdx.x, lane = t & 63, w = t >> 6;
    int lo = 0, hi = N;
    while (lo < hi) { int m = (lo + hi) >> 1; if (batch[m] < g) lo = m + 1; else hi = m; }
    int s0 = lo;
    hi = N;
    while (lo < hi) { int m = (lo + hi) >> 1; if (batch[m] < g + 1) lo = m + 1; else hi = m; }
    int s1 = lo;
    float s = 0.f;
    for (int n = s0 + w; n < s1; n += 4) s += h[(size_t)n * 64 + lane];
    part[w][lane] = s;
    __syncthreads();
    if (t < 64) {
        float c = fmaxf((float)(s1 - s0), 1.f);
        sh[t] = (part[0][t] + part[1][t] + part[2][t] + part[3][t]) / c;
    }
    __syncthreads();
    if (t < 32) {
        float a = fc1b[t];
        #pragma unroll
        for (int o = 0; o < 64; ++o) a += sh[o] * fc1w[o * 32 + t];
        sh2[t] = fmaxf(a, 0.f);
    }
    __syncthreads();
    if (t == 0) {
        float a = fc2b[0];
        #pragma unroll
        for (int j = 0; j < 32; ++j) a += sh2[j] * fc2w[j];
        out[g] = a;
    }
}

extern "C" void kernel_launch(void* const* d_in, const int* in_sizes, int n_in,
                              void* d_out, int out_size, void* d_ws, size_t ws_size,
                              hipStream_t stream) {
    const float* x     = (const float*)d_in[0];
    const int*   ei    = (const int*)d_in[1];
    const float* ea    = (const float*)d_in[2];
    const int*   batch = (const int*)d_in[3];
    int E = in_sizes[1] / 2;
    int N = in_sizes[3];
    int G = out_size;  // DOUT = 1
    const int* src  = ei;
    const int* dstv = ei + E;

    const float* P[24];
    for (int i = 0; i < 24; ++i) P[i] = (const float*)d_in[4 + i];
    const float* fc1w = (const float*)d_in[28];
    const float* fc1b = (const float*)d_in[29];
    const float* fc2w = (const float*)d_in[30];
    const float* fc2b = (const float*)d_in[31];

    // workspace layout
    float* hA  = (float*)d_ws;                 // N*64 f32
    float* hB  = hA + (size_t)N * 64;          // N*64 f32
    short* zge = (short*)(hB + (size_t)N * 64);// E*64 bf16 (z rows, h-half-major)
    short* xbA = zge + (size_t)E * 64;         // N*64 bf16
    short* xbB = xbA + (size_t)N * 64;         // N*64 bf16
    short* w2a = xbB + (size_t)N * 64;         // 65*64*64 bf16, fragment-ordered

    int ebl   = (E + 63) / 64;
    int mbl   = ebl * 2;                       // h-split pairs
    int n64   = (N * 64 + 255) / 256;
    int nln   = (N + 3) / 4;
    int pb64  = (65 * 4 * 1024 + 255) / 256;   // prep blocks, CIN=64
    int pb32  = (65 * 2 * 1024 + 255) / 256;   // prep blocks, CIN=32

    k_cvt<<<(N * 32 + 255) / 256, 256, 0, stream>>>(x, xbA, N * 32);

    // ---- layer 1 (cin = 32) ----
    k_edge_prep<32><<<ebl + pb32, 256, 0, stream>>>(ea, P[0], P[1], zge, E, ebl, P[2], P[3], w2a);
    k_root32<<<n64, 256, 0, stream>>>(x, P[4], P[5], hA, N);
    k_msg<32><<<mbl, 256, 0, stream>>>(zge, xbA, src, dstv, w2a, hA, E);

    // ---- layer 2 (cin = 64) ----
    k_edge_prep<64><<<ebl + pb64, 256, 0, stream>>>(ea, P[8], P[9], zge, E, ebl, P[10], P[11], w2a);
    k_ln_root<<<nln, 256, 0, stream>>>(hA, P[6], P[7], P[12], P[13], xbB, hB, N);
    k_msg<64><<<mbl, 256, 0, stream>>>(zge, xbB, src, dstv, w2a, hB, E);

    // ---- layer 3 (cin = 64) ----
    k_edge_prep<64><<<ebl + pb64, 256, 0, stream>>>(ea, P[16], P[17], zge, E, ebl, P[18], P[19], w2a);
    k_ln_root<<<nln, 256, 0, stream>>>(hB, P[14], P[15], P[20], P[21], xbA, hA, N);
    k_msg<64><<<mbl, 256, 0, stream>>>(zge, xbA, src, dstv, w2a, hA, E);
    k_ln<<<nln, 256, 0, stream>>>(hA, P[22], P[23], N);

    // ---- fused pool + head ----
    k_pool_head<<<G, 256, 0, stream>>>(hA, batch, fc1w, fc1b, fc2w, fc2b, (float*)d_out, N);
}